// Round 3
// baseline (198.892 us; speedup 1.0000x reference)
//
#include <hip/hip_runtime.h>

#define B_ 4
#define C_ 256
#define N_ 4096
#define D_ 64

typedef __bf16 bf16x8 __attribute__((ext_vector_type(8)));
typedef float floatx4 __attribute__((ext_vector_type(4)));
typedef unsigned short ushort8v __attribute__((ext_vector_type(8)));
typedef unsigned short ushort4v __attribute__((ext_vector_type(4)));
typedef unsigned short ushort2v __attribute__((ext_vector_type(2)));

static __device__ __forceinline__ unsigned short f2bf(float f) {
    unsigned int u = __builtin_bit_cast(unsigned int, f);
    u += 0x7fffu + ((u >> 16) & 1u);   // RNE
    return (unsigned short)(u >> 16);
}
static __device__ __forceinline__ float bf2f(unsigned short h) {
    unsigned int u = ((unsigned int)h) << 16;
    return __builtin_bit_cast(float, u);
}

// async global->LDS DMA, 16B/lane, dst = wave-uniform base + lane*16
#define GLOAD16(gp, lp)                                                      \
    __builtin_amdgcn_global_load_lds(                                        \
        (const __attribute__((address_space(1))) void*)(gp),                 \
        (__attribute__((address_space(3))) void*)(lp), 16, 0, 0)

// ---------------------------------------------------------------------------
// One-time W conversion into A-frag-native layout (unchanged).
// ---------------------------------------------------------------------------
__global__ __launch_bounds__(256) void convert_w(
    const float* __restrict__ Wq, const float* __restrict__ Wk,
    const float* __restrict__ Wv, unsigned short* __restrict__ WbfA)
{
    int tid = blockIdx.x * 256 + threadIdx.x;   // 0..24575
    int p0  = tid * 4;                          // output short index
    int j0   = p0 & 7;
    int lane = (p0 >> 3) & 63;
    int sidx = p0 >> 9;
    int ft = sidx >> 3, ks = sidx & 7;
    int m  = lane & 15, g = lane >> 4;
    int f  = 16*ft + m;
    int c  = 32*ks + 8*g + j0;
    const float* src = (f < 64)  ? (Wq + (size_t)f * C_)
                     : (f < 128) ? (Wk + (size_t)(f - 64) * C_)
                                 : (Wv + (size_t)(f - 128) * C_);
    float4 v = *(const float4*)(src + c);
    ushort4v u;
    u[0] = f2bf(v.x); u[1] = f2bf(v.y); u[2] = f2bf(v.z); u[3] = f2bf(v.w);
    *(ushort4v*)(WbfA + p0) = u;
}

// ---------------------------------------------------------------------------
// MFMA projection (unchanged).
// ---------------------------------------------------------------------------
__global__ __launch_bounds__(256, 3) void proj_kernel(
    const float* __restrict__ x, const unsigned short* __restrict__ WbfA,
    const float* __restrict__ bq, const float* __restrict__ bk,
    const float* __restrict__ bv,
    unsigned short* __restrict__ Qg, unsigned short* __restrict__ Kg,
    unsigned short* __restrict__ Vg)
{
    __shared__ __align__(16) unsigned short smem[64 * 264];  // 33792 B
    unsigned short* xs = smem;          // x tile, swizzled [n][264]
    unsigned short* Lt = smem;          // epilogue tile [128][72] (union)

    const int n0 = blockIdx.x * 64;
    const int f0 = blockIdx.y * 128;
    const int b  = blockIdx.z;
    const int t  = threadIdx.x;
    const int w  = t >> 6;
    const int lane = t & 63;
    const int g  = lane >> 4;
    const int m  = lane & 15;

#pragma unroll
    for (int k = 0; k < 8; ++k) {
        int e  = t + 256 * k;           // 0..2047
        int cp = e >> 4;                // 0..127
        int c  = 2 * cp;
        int n4 = (e & 15) * 4;
        float4 v0 = *(const float4*)(x + ((size_t)b*C_ + c    )*N_ + n0 + n4);
        float4 v1 = *(const float4*)(x + ((size_t)b*C_ + c + 1)*N_ + n0 + n4);
        float a0[4] = {v0.x, v0.y, v0.z, v0.w};
        float a1[4] = {v1.x, v1.y, v1.z, v1.w};
#pragma unroll
        for (int j = 0; j < 4; ++j) {
            int n = n4 + j;
            ushort2v u2;
            u2[0] = f2bf(a0[j]);
            u2[1] = f2bf(a1[j]);
            *(ushort2v*)&xs[n*264 + (((c >> 3) ^ (n & 7)) << 3) + (c & 7)] = u2;
        }
    }

    float bias_[2][4];
#pragma unroll
    for (int mt = 0; mt < 2; ++mt)
#pragma unroll
        for (int r = 0; r < 4; ++r) {
            int fg = f0 + 32*w + 16*mt + 4*g + r;
            bias_[mt][r] = (fg < 64) ? bq[fg]
                         : (fg < 128) ? bk[fg - 64] : bv[fg - 128];
        }

    const unsigned short* Wa0 = WbfA + (size_t)(((f0 >> 4) + 2*w    )*8)*512
                              + lane*8;
    const unsigned short* Wa1 = WbfA + (size_t)(((f0 >> 4) + 2*w + 1)*8)*512
                              + lane*8;

    floatx4 acc[2][4];
#pragma unroll
    for (int mt = 0; mt < 2; ++mt)
#pragma unroll
        for (int nt = 0; nt < 4; ++nt) acc[mt][nt] = (floatx4){0.f,0.f,0.f,0.f};

    __syncthreads();   // x tile staged

#pragma unroll
    for (int ks = 0; ks < 8; ++ks) {
        bf16x8 af[2];
        af[0] = *(const bf16x8*)(Wa0 + ks*512);
        af[1] = *(const bf16x8*)(Wa1 + ks*512);
#pragma unroll
        for (int nt = 0; nt < 4; ++nt) {
            int n = 16*nt + m;
            bf16x8 bfr = *(const bf16x8*)
                &xs[n*264 + (((4*ks + g) ^ (n & 7)) << 3)];
#pragma unroll
            for (int mt = 0; mt < 2; ++mt)
                acc[mt][nt] = __builtin_amdgcn_mfma_f32_16x16x32_bf16(
                                  af[mt], bfr, acc[mt][nt], 0, 0, 0);
        }
    }

    __syncthreads();   // xs dead -> Lt overlay

#pragma unroll
    for (int mt = 0; mt < 2; ++mt)
#pragma unroll
        for (int nt = 0; nt < 4; ++nt)
#pragma unroll
            for (int r = 0; r < 4; ++r)
                Lt[(32*w + 16*mt + 4*g + r)*72 + 16*nt + m] =
                    f2bf(acc[mt][nt][r] + bias_[mt][r]);
    __syncthreads();

    if (f0 == 0) {
#pragma unroll
        for (int k = 0; k < 4; ++k) {
            int e   = t + 256 * k;
            int fq0 = (e >> 6) * 8;
            int nl  = e & 63;
            ushort8v u;
#pragma unroll
            for (int j = 0; j < 8; ++j) u[j] = Lt[(fq0 + j)*72 + nl];
            unsigned short* dst = (fq0 < 64)
                ? (Qg + ((size_t)b*N_ + n0 + nl)*D_ + fq0)
                : (Kg + ((size_t)b*N_ + n0 + nl)*D_ + (fq0 - 64));
            *(ushort8v*)dst = u;
        }
    } else {
        const int cb = f0 - 128;
#pragma unroll
        for (int k = 0; k < 4; ++k) {
            int e  = t + 256 * k;
            int fr = e >> 3;
            int n8 = (e & 7) * 8;
            ushort8v u = *(const ushort8v*)&Lt[fr*72 + n8];
            *(ushort8v*)(Vg + ((size_t)b*C_ + cb + fr)*N_ + n0 + n8) = u;
        }
    }
}

// ---------------------------------------------------------------------------
// MFMA flash attention: 128-query tiles, 8 waves, split-K 4 so the grid is
// 512 blocks = 2 blocks/CU = 16 waves/CU (4 waves/SIMD). R0/R2 both ran
// 2 waves/SIMD and tied at ~87-91us with no pipe >45% busy -> latency-bound.
// Doubling waves/SIMD doubles latency hiding; cross-block phase diversity
// also lets one block's PV cover the other's V-DMA drain (+setprio on PV).
// ---------------------------------------------------------------------------
__global__ __launch_bounds__(512, 4) void flash_kernel(
    const unsigned short* __restrict__ Qg, const unsigned short* __restrict__ Kg,
    const unsigned short* __restrict__ Vg,
    unsigned short* __restrict__ Opart, float* __restrict__ ML)
{
    __shared__ __align__(16) unsigned short Vlds[32 * 512];    // 32 KB
    __shared__ __align__(16) unsigned short Klds[2][8 * 512];  // 16 KB
    __shared__ __align__(16) unsigned short PA[16 * 64 * 8];   // 16 KB
    __shared__ float AL[128];

    const int gx   = blockIdx.x;        // quarter + 4*b  (XCD pin)
    const int tile = blockIdx.y;        // 0..31 (128-query tiles)
    const int quarter = gx & 3;
    const int b    = gx >> 2;
    const int n0   = tile * 128;
    const int t    = threadIdx.x;
    const int w    = t >> 6;            // 0..7
    const int lane = t & 63;
    const int g    = lane >> 4;
    const int m    = lane & 15;
    const int wq   = w >> 2;            // PV: query-half (0..1)
    const int cq   = w & 3;             // PV: channel-quarter (0..3)

    const unsigned short* Qb = Qg + ((size_t)b*N_ + n0)*D_;
    const unsigned short* Kb = Kg + (size_t)b*N_*D_;
    const unsigned short* Vb = Vg + (size_t)b*C_*N_;

    const int cstart = quarter * 16;
    const int cend   = cstart + 16;

    bf16x8 qf[2];
#pragma unroll
    for (int ks = 0; ks < 2; ++ks)
        qf[ks] = *(const bf16x8*)(Qb + (size_t)(16*w + m)*D_ + 32*ks + 8*g);

    floatx4 accO[4][4];
#pragma unroll
    for (int rt = 0; rt < 4; ++rt)
#pragma unroll
        for (int ct = 0; ct < 4; ++ct)
            accO[rt][ct] = (floatx4){0.f, 0.f, 0.f, 0.f};

    float mrow = -1e30f, lrow = 0.f;

    // prologue: DMA K(cstart) into Klds[0] (one 1KB wave-op per wave)
    {
        const unsigned short* gp =
            Kb + (size_t)(cstart*64 + 16*(w >> 1) + m)*D_ + 32*(w & 1) + 8*g;
        GLOAD16(gp, &Klds[0][w * 512]);
    }
    __syncthreads();

    for (int t64 = cstart; t64 < cend; ++t64) {
        const int j0 = t64 * 64;
        const int kb = (t64 - cstart) & 1;

        // DMA V(t64): 4 wave-ops per wave (32 total)
#pragma unroll
        for (int u = 0; u < 4; ++u) {
            int sidx = 4*w + u;
            int ks   = sidx >> 4;
            int cb   = sidx & 15;
            const unsigned short* gp =
                Vb + (size_t)(16*cb + m)*N_ + j0 + 32*ks + 8*g;
            GLOAD16(gp, &Vlds[sidx * 512]);
        }
        // DMA K(t64+1) into other buffer (1 wave-op per wave)
        if (t64 + 1 < cend) {
            const unsigned short* gp =
                Kb + (size_t)((t64+1)*64 + 16*(w >> 1) + m)*D_
                   + 32*(w & 1) + 8*g;
            GLOAD16(gp, &Klds[kb ^ 1][w * 512]);
        }

        // S^T = K*Q from Klds[kb]; each wave: its 16 queries x 64 keys
        floatx4 accST[4];
#pragma unroll
        for (int jt = 0; jt < 4; ++jt) accST[jt] = (floatx4){0.f,0.f,0.f,0.f};
#pragma unroll
        for (int ks = 0; ks < 2; ++ks)
#pragma unroll
            for (int jt = 0; jt < 4; ++jt) {
                bf16x8 kfr = *(const bf16x8*)
                    &Klds[kb][(jt*2 + ks)*512 + lane*8];
                accST[jt] = __builtin_amdgcn_mfma_f32_16x16x32_bf16(
                                kfr, qf[ks], accST[jt], 0, 0, 0);
            }

        // online softmax: in-register over 16 keys/lane + 2 shfls
        float mx = -1e30f;
#pragma unroll
        for (int jt = 0; jt < 4; ++jt)
#pragma unroll
            for (int r = 0; r < 4; ++r) mx = fmaxf(mx, accST[jt][r]);
        mx = fmaxf(mx, __shfl_xor(mx, 16));
        mx = fmaxf(mx, __shfl_xor(mx, 32));
        float mnew  = fmaxf(mrow, mx);
        float alpha = __expf(mrow - mnew);
        mrow = mnew;
        float p[4][4];
        float rs = 0.f;
#pragma unroll
        for (int jt = 0; jt < 4; ++jt)
#pragma unroll
            for (int r = 0; r < 4; ++r) {
                float e = __expf(accST[jt][r] - mnew);
                p[jt][r] = e;
                rs += e;
            }
        rs += __shfl_xor(rs, 16);
        rs += __shfl_xor(rs, 32);
        lrow = lrow * alpha + rs;

        if (g == 0) AL[16*w + m] = alpha;

        // P -> LDS, direct b64 stores into A-frag layout (16 groups)
#pragma unroll
        for (int jt = 0; jt < 4; ++jt) {
            ushort4v u;
#pragma unroll
            for (int r = 0; r < 4; ++r) u[r] = f2bf(p[jt][r]);
            int frag = (w*2 + (jt >> 1))*64 + 16*(2*(jt & 1) + (g >> 1)) + m;
            *(ushort4v*)&PA[frag*8 + 4*(g & 1)] = u;
        }

        __syncthreads();   // barrier A: drains V DMA (+K prefetch)

        // PV: O = alpha*O + P V; wave covers query-half wq x channel-qtr cq
#pragma unroll
        for (int rt = 0; rt < 4; ++rt) {
            floatx4 a4 = *(const floatx4*)&AL[64*wq + 16*rt + 4*g];
#pragma unroll
            for (int ct = 0; ct < 4; ++ct)
                accO[rt][ct] *= a4;
        }
        __builtin_amdgcn_s_setprio(1);
#pragma unroll
        for (int ks = 0; ks < 2; ++ks) {
            bf16x8 pf[4];
#pragma unroll
            for (int rt = 0; rt < 4; ++rt)
                pf[rt] = *(const bf16x8*)
                    &PA[((8*wq + rt*2 + ks)*64 + lane)*8];
#pragma unroll
            for (int ct = 0; ct < 4; ++ct) {
                int sidx = ks*16 + 4*cq + ct;
                bf16x8 vfrag = *(const bf16x8*)&Vlds[sidx*512 + lane*8];
#pragma unroll
                for (int rt = 0; rt < 4; ++rt)
                    accO[rt][ct] = __builtin_amdgcn_mfma_f32_16x16x32_bf16(
                                       pf[rt], vfrag, accO[rt][ct], 0, 0, 0);
            }
        }
        __builtin_amdgcn_s_setprio(0);

        __syncthreads();   // barrier B
    }

    // store unnormalized partial O (bf16) and per-query m,l
    const size_t tbase = ((size_t)(quarter*B_ + b)*32 + tile);
    unsigned short* Ob = Opart + tbase * (C_ * 128);
    float* ml = ML + tbase * 256;

    if (g == 0) {
        ml[16*w + m]       = mrow;
        ml[128 + 16*w + m] = lrow;
    }

#pragma unroll
    for (int rt = 0; rt < 4; ++rt)
#pragma unroll
        for (int ct = 0; ct < 4; ++ct) {
            int c  = 64*cq + 16*ct + m;
            int q0 = 64*wq + 16*rt + 4*g;
            ushort4v u4;
#pragma unroll
            for (int r = 0; r < 4; ++r) u4[r] = f2bf(accO[rt][ct][r]);
            *(ushort4v*)(Ob + (size_t)c*128 + q0) = u4;
        }
}

// ---------------------------------------------------------------------------
// Combine: S=4 static, c-split across 2 blocks, 128-query tiles.
// ---------------------------------------------------------------------------
__global__ __launch_bounds__(256) void combine_kernel(
    const unsigned short* __restrict__ Opart, const float* __restrict__ ML,
    const float* __restrict__ x, const float* __restrict__ gamma,
    float* __restrict__ out)
{
    __shared__ float sc[4][128];
    const int tile  = blockIdx.x;       // 0..31
    const int chalf = blockIdx.y;
    const int b     = blockIdx.z;
    const int n0    = tile * 128;
    const int t     = threadIdx.x;

    if (t < 128) {
        float mm[4], ll[4];
        float M = -1e30f;
#pragma unroll
        for (int s = 0; s < 4; ++s) {
            const float* mls = ML + ((size_t)(s*B_ + b)*32 + tile)*256;
            mm[s] = mls[t];
            ll[s] = mls[128 + t];
            M = fmaxf(M, mm[s]);
        }
        float fs[4];
        float L = 0.f;
#pragma unroll
        for (int s = 0; s < 4; ++s) { fs[s] = __expf(mm[s] - M); L += fs[s]*ll[s]; }
        float gm = gamma[0];
#pragma unroll
        for (int s = 0; s < 4; ++s) sc[s][t] = gm * fs[s] / L;
    }
    __syncthreads();

    const int nq = t & 31;              // query-quad (float4 column)
    const int cl = t >> 5;              // 0..7
    const float* xb = x   + (size_t)b*C_*N_;
    float*       ob = out + (size_t)b*C_*N_;
    const unsigned short* Os[4];
#pragma unroll
    for (int s = 0; s < 4; ++s)
        Os[s] = Opart + ((size_t)(s*B_ + b)*32 + tile)*(C_*128);

    float sv[4][4];
#pragma unroll
    for (int s = 0; s < 4; ++s)
#pragma unroll
        for (int k = 0; k < 4; ++k) sv[s][k] = sc[s][4*nq + k];

#pragma unroll 4
    for (int i = 0; i < 16; ++i) {
        int c = 128*chalf + 8*i + cl;
        float4 x4 = *(const float4*)(xb + (size_t)c*N_ + n0 + 4*nq);
        float4 y = x4;
#pragma unroll
        for (int s = 0; s < 4; ++s) {
            ushort4v a4 = *(const ushort4v*)(Os[s] + (size_t)c*128 + 4*nq);
            y.x += sv[s][0]*bf2f(a4[0]);
            y.y += sv[s][1]*bf2f(a4[1]);
            y.z += sv[s][2]*bf2f(a4[2]);
            y.w += sv[s][3]*bf2f(a4[3]);
        }
        *(float4*)(ob + (size_t)c*N_ + n0 + 4*nq) = y;
    }
}

// ---------------------------------------------------------------------------
extern "C" void kernel_launch(void* const* d_in, const int* in_sizes, int n_in,
                              void* d_out, int out_size, void* d_ws, size_t ws_size,
                              hipStream_t stream) {
    const float* x     = (const float*)d_in[0];
    const float* Wq    = (const float*)d_in[1];
    const float* bq    = (const float*)d_in[2];
    const float* Wk    = (const float*)d_in[3];
    const float* bk    = (const float*)d_in[4];
    const float* Wv    = (const float*)d_in[5];
    const float* bv    = (const float*)d_in[6];
    const float* gamma = (const float*)d_in[7];
    float* out = (float*)d_out;

    // ws layout (~46.3 MB):
    unsigned short* Qg = (unsigned short*)d_ws;            // 2 MiB
    unsigned short* Kg = Qg + (size_t)B_*N_*D_;            // 2 MiB
    unsigned short* Vg = Kg + (size_t)B_*N_*D_;            // 8 MiB
    unsigned short* Op = Vg + (size_t)B_*C_*N_;            // 32 MiB (S=4)
    float* ML = (float*)(Op + (size_t)4*B_*32*C_*128);     // 512 KiB
    unsigned short* WbfA = (unsigned short*)(ML + (size_t)4*B_*32*256); // 192 KiB

    convert_w<<<dim3(96), 256, 0, stream>>>(Wq, Wk, Wv, WbfA);
    proj_kernel<<<dim3(64, 3, 4), 256, 0, stream>>>(x, WbfA, bq, bk, bv,
                                                    Qg, Kg, Vg);
    flash_kernel<<<dim3(16, 32), 512, 0, stream>>>(Qg, Kg, Vg, Op, ML);
    combine_kernel<<<dim3(32, 2, 4), 256, 0, stream>>>(Op, ML, x, gamma, out);
}

// Round 4
// 191.847 us; speedup vs baseline: 1.0367x; 1.0367x over previous
//
#include <hip/hip_runtime.h>

#define B_ 4
#define C_ 256
#define N_ 4096
#define D_ 64

typedef __bf16 bf16x8 __attribute__((ext_vector_type(8)));
typedef float floatx4 __attribute__((ext_vector_type(4)));
typedef unsigned short ushort8v __attribute__((ext_vector_type(8)));
typedef unsigned short ushort4v __attribute__((ext_vector_type(4)));
typedef unsigned short ushort2v __attribute__((ext_vector_type(2)));

static __device__ __forceinline__ unsigned short f2bf(float f) {
    unsigned int u = __builtin_bit_cast(unsigned int, f);
    u += 0x7fffu + ((u >> 16) & 1u);   // RNE
    return (unsigned short)(u >> 16);
}
static __device__ __forceinline__ float bf2f(unsigned short h) {
    unsigned int u = ((unsigned int)h) << 16;
    return __builtin_bit_cast(float, u);
}

// async global->LDS DMA, 16B/lane, dst = wave-uniform base + lane*16
#define GLOAD16(gp, lp)                                                      \
    __builtin_amdgcn_global_load_lds(                                        \
        (const __attribute__((address_space(1))) void*)(gp),                 \
        (__attribute__((address_space(3))) void*)(lp), 16, 0, 0)

// ---------------------------------------------------------------------------
// One-time W conversion into A-frag-native layout (unchanged).
// ---------------------------------------------------------------------------
__global__ __launch_bounds__(256) void convert_w(
    const float* __restrict__ Wq, const float* __restrict__ Wk,
    const float* __restrict__ Wv, unsigned short* __restrict__ WbfA)
{
    int tid = blockIdx.x * 256 + threadIdx.x;   // 0..24575
    int p0  = tid * 4;                          // output short index
    int j0   = p0 & 7;
    int lane = (p0 >> 3) & 63;
    int sidx = p0 >> 9;
    int ft = sidx >> 3, ks = sidx & 7;
    int m  = lane & 15, g = lane >> 4;
    int f  = 16*ft + m;
    int c  = 32*ks + 8*g + j0;
    const float* src = (f < 64)  ? (Wq + (size_t)f * C_)
                     : (f < 128) ? (Wk + (size_t)(f - 64) * C_)
                                 : (Wv + (size_t)(f - 128) * C_);
    float4 v = *(const float4*)(src + c);
    ushort4v u;
    u[0] = f2bf(v.x); u[1] = f2bf(v.y); u[2] = f2bf(v.z); u[3] = f2bf(v.w);
    *(ushort4v*)(WbfA + p0) = u;
}

// ---------------------------------------------------------------------------
// MFMA projection (unchanged).
// ---------------------------------------------------------------------------
__global__ __launch_bounds__(256, 3) void proj_kernel(
    const float* __restrict__ x, const unsigned short* __restrict__ WbfA,
    const float* __restrict__ bq, const float* __restrict__ bk,
    const float* __restrict__ bv,
    unsigned short* __restrict__ Qg, unsigned short* __restrict__ Kg,
    unsigned short* __restrict__ Vg)
{
    __shared__ __align__(16) unsigned short smem[64 * 264];  // 33792 B
    unsigned short* xs = smem;          // x tile, swizzled [n][264]
    unsigned short* Lt = smem;          // epilogue tile [128][72] (union)

    const int n0 = blockIdx.x * 64;
    const int f0 = blockIdx.y * 128;
    const int b  = blockIdx.z;
    const int t  = threadIdx.x;
    const int w  = t >> 6;
    const int lane = t & 63;
    const int g  = lane >> 4;
    const int m  = lane & 15;

#pragma unroll
    for (int k = 0; k < 8; ++k) {
        int e  = t + 256 * k;           // 0..2047
        int cp = e >> 4;                // 0..127
        int c  = 2 * cp;
        int n4 = (e & 15) * 4;
        float4 v0 = *(const float4*)(x + ((size_t)b*C_ + c    )*N_ + n0 + n4);
        float4 v1 = *(const float4*)(x + ((size_t)b*C_ + c + 1)*N_ + n0 + n4);
        float a0[4] = {v0.x, v0.y, v0.z, v0.w};
        float a1[4] = {v1.x, v1.y, v1.z, v1.w};
#pragma unroll
        for (int j = 0; j < 4; ++j) {
            int n = n4 + j;
            ushort2v u2;
            u2[0] = f2bf(a0[j]);
            u2[1] = f2bf(a1[j]);
            *(ushort2v*)&xs[n*264 + (((c >> 3) ^ (n & 7)) << 3) + (c & 7)] = u2;
        }
    }

    float bias_[2][4];
#pragma unroll
    for (int mt = 0; mt < 2; ++mt)
#pragma unroll
        for (int r = 0; r < 4; ++r) {
            int fg = f0 + 32*w + 16*mt + 4*g + r;
            bias_[mt][r] = (fg < 64) ? bq[fg]
                         : (fg < 128) ? bk[fg - 64] : bv[fg - 128];
        }

    const unsigned short* Wa0 = WbfA + (size_t)(((f0 >> 4) + 2*w    )*8)*512
                              + lane*8;
    const unsigned short* Wa1 = WbfA + (size_t)(((f0 >> 4) + 2*w + 1)*8)*512
                              + lane*8;

    floatx4 acc[2][4];
#pragma unroll
    for (int mt = 0; mt < 2; ++mt)
#pragma unroll
        for (int nt = 0; nt < 4; ++nt) acc[mt][nt] = (floatx4){0.f,0.f,0.f,0.f};

    __syncthreads();   // x tile staged

#pragma unroll
    for (int ks = 0; ks < 8; ++ks) {
        bf16x8 af[2];
        af[0] = *(const bf16x8*)(Wa0 + ks*512);
        af[1] = *(const bf16x8*)(Wa1 + ks*512);
#pragma unroll
        for (int nt = 0; nt < 4; ++nt) {
            int n = 16*nt + m;
            bf16x8 bfr = *(const bf16x8*)
                &xs[n*264 + (((4*ks + g) ^ (n & 7)) << 3)];
#pragma unroll
            for (int mt = 0; mt < 2; ++mt)
                acc[mt][nt] = __builtin_amdgcn_mfma_f32_16x16x32_bf16(
                                  af[mt], bfr, acc[mt][nt], 0, 0, 0);
        }
    }

    __syncthreads();   // xs dead -> Lt overlay

#pragma unroll
    for (int mt = 0; mt < 2; ++mt)
#pragma unroll
        for (int nt = 0; nt < 4; ++nt)
#pragma unroll
            for (int r = 0; r < 4; ++r)
                Lt[(32*w + 16*mt + 4*g + r)*72 + 16*nt + m] =
                    f2bf(acc[mt][nt][r] + bias_[mt][r]);
    __syncthreads();

    if (f0 == 0) {
#pragma unroll
        for (int k = 0; k < 4; ++k) {
            int e   = t + 256 * k;
            int fq0 = (e >> 6) * 8;
            int nl  = e & 63;
            ushort8v u;
#pragma unroll
            for (int j = 0; j < 8; ++j) u[j] = Lt[(fq0 + j)*72 + nl];
            unsigned short* dst = (fq0 < 64)
                ? (Qg + ((size_t)b*N_ + n0 + nl)*D_ + fq0)
                : (Kg + ((size_t)b*N_ + n0 + nl)*D_ + (fq0 - 64));
            *(ushort8v*)dst = u;
        }
    } else {
        const int cb = f0 - 128;
#pragma unroll
        for (int k = 0; k < 4; ++k) {
            int e  = t + 256 * k;
            int fr = e >> 3;
            int n8 = (e & 7) * 8;
            ushort8v u = *(const ushort8v*)&Lt[fr*72 + n8];
            *(ushort8v*)(Vg + ((size_t)b*C_ + cb + fr)*N_ + n0 + n8) = u;
        }
    }
}

// ---------------------------------------------------------------------------
// MFMA flash attention: one-tile-lag software pipeline (T15).
// Iteration t: [barrier: drains V(t-1)+K(t) DMA, syncs P(t-1)] ->
// issue V(t)+K(t+1) DMA -> ST(t) MFMA -> PV(t-1) MFMA (independent of
// softmax(t), overlaps it on the matrix pipe) -> softmax(t) VALU ->
// P(t)->PA[t&1]. ONE barrier per tile (was 2); V DMA gets a full
// iteration of cover. V/K/PA/AL all double-buffered: 113 KB LDS,
// 1 block x 8 waves per CU (R2 geometry/traffic, proven sufficient).
// ---------------------------------------------------------------------------
__global__ __launch_bounds__(512, 2) void flash_kernel(
    const unsigned short* __restrict__ Qg, const unsigned short* __restrict__ Kg,
    const unsigned short* __restrict__ Vg,
    unsigned short* __restrict__ Opart, float* __restrict__ ML)
{
    __shared__ __align__(16) unsigned short Vlds[2][32 * 512];   // 64 KB
    __shared__ __align__(16) unsigned short Klds[2][8 * 512];    // 16 KB
    __shared__ __align__(16) unsigned short PA[2][16 * 64 * 8];  // 32 KB
    __shared__ float AL[2][128];                                 //  1 KB

    const int g8   = blockIdx.x;        // half + 2*b  (XCD pin)
    const int tile = blockIdx.y;        // 0..31 (128-query tiles)
    const int half = g8 & 1;
    const int b    = g8 >> 1;
    const int n0   = tile * 128;
    const int t    = threadIdx.x;
    const int w    = t >> 6;            // 0..7
    const int lane = t & 63;
    const int g    = lane >> 4;
    const int m    = lane & 15;
    const int wq   = w >> 2;            // PV: query-half (0..1)
    const int cq   = w & 3;             // PV: channel-quarter (0..3)

    const unsigned short* Qb = Qg + ((size_t)b*N_ + n0)*D_;
    const unsigned short* Kb = Kg + (size_t)b*N_*D_;
    const unsigned short* Vb = Vg + (size_t)b*C_*N_;

    const int cstart = half * 32;       // even -> parity (t64&1) starts at 0
    const int cend   = cstart + 32;

    bf16x8 qf[2];
#pragma unroll
    for (int ks = 0; ks < 2; ++ks)
        qf[ks] = *(const bf16x8*)(Qb + (size_t)(16*w + m)*D_ + 32*ks + 8*g);

    floatx4 accO[4][4];
#pragma unroll
    for (int rt = 0; rt < 4; ++rt)
#pragma unroll
        for (int ct = 0; ct < 4; ++ct)
            accO[rt][ct] = (floatx4){0.f, 0.f, 0.f, 0.f};

    float mrow = -1e30f, lrow = 0.f;

    // prologue: DMA K(cstart) into Klds[0] (one 1KB wave-op per wave)
    {
        const unsigned short* gp =
            Kb + (size_t)(cstart*64 + 16*(w >> 1) + m)*D_ + 32*(w & 1) + 8*g;
        GLOAD16(gp, &Klds[0][w * 512]);
    }

    for (int t64 = cstart; t64 < cend; ++t64) {
        const int cur = t64 & 1;
        const int j0  = t64 * 64;

        // barrier: drains this wave's V(t64-1)+K(t64) DMAs (vmcnt0) and
        // makes P(t64-1)/AL(t64-1) visible; syncs PV(t64-2) buffer reuse.
        __syncthreads();

        // issue V(t64) DMA -> Vlds[cur]: 4 wave-ops per wave (32 total)
#pragma unroll
        for (int u = 0; u < 4; ++u) {
            int sidx = 4*w + u;
            int ks   = sidx >> 4;
            int cb   = sidx & 15;
            const unsigned short* gp =
                Vb + (size_t)(16*cb + m)*N_ + j0 + 32*ks + 8*g;
            GLOAD16(gp, &Vlds[cur][sidx * 512]);
        }
        // issue K(t64+1) DMA -> Klds[cur^1] (1 wave-op per wave)
        if (t64 + 1 < cend) {
            const unsigned short* gp =
                Kb + (size_t)((t64+1)*64 + 16*(w >> 1) + m)*D_
                   + 32*(w & 1) + 8*g;
            GLOAD16(gp, &Klds[cur ^ 1][w * 512]);
        }

        // ST(t64) = K*Q from Klds[cur]; wave: its 16 queries x 64 keys
        floatx4 accST[4];
#pragma unroll
        for (int jt = 0; jt < 4; ++jt) accST[jt] = (floatx4){0.f,0.f,0.f,0.f};
#pragma unroll
        for (int ks = 0; ks < 2; ++ks)
#pragma unroll
            for (int jt = 0; jt < 4; ++jt) {
                bf16x8 kfr = *(const bf16x8*)
                    &Klds[cur][(jt*2 + ks)*512 + lane*8];
                accST[jt] = __builtin_amdgcn_mfma_f32_16x16x32_bf16(
                                kfr, qf[ks], accST[jt], 0, 0, 0);
            }

        // PV(t64-1): independent of softmax(t64) -> overlaps it.
        if (t64 > cstart) {
#pragma unroll
            for (int rt = 0; rt < 4; ++rt) {
                floatx4 a4 = *(const floatx4*)
                    &AL[cur ^ 1][64*wq + 16*rt + 4*g];
#pragma unroll
                for (int ct = 0; ct < 4; ++ct)
                    accO[rt][ct] *= a4;
            }
            __builtin_amdgcn_s_setprio(1);
#pragma unroll
            for (int ks = 0; ks < 2; ++ks) {
                bf16x8 pf[4];
#pragma unroll
                for (int rt = 0; rt < 4; ++rt)
                    pf[rt] = *(const bf16x8*)
                        &PA[cur ^ 1][((8*wq + rt*2 + ks)*64 + lane)*8];
#pragma unroll
                for (int ct = 0; ct < 4; ++ct) {
                    int sidx = ks*16 + 4*cq + ct;
                    bf16x8 vfrag = *(const bf16x8*)
                        &Vlds[cur ^ 1][sidx*512 + lane*8];
#pragma unroll
                    for (int rt = 0; rt < 4; ++rt)
                        accO[rt][ct] = __builtin_amdgcn_mfma_f32_16x16x32_bf16(
                                           pf[rt], vfrag, accO[rt][ct], 0, 0, 0);
                }
            }
            __builtin_amdgcn_s_setprio(0);
        }

        // softmax(t64): in-register over 16 keys/lane + 2 shfls
        float mx = -1e30f;
#pragma unroll
        for (int jt = 0; jt < 4; ++jt)
#pragma unroll
            for (int r = 0; r < 4; ++r) mx = fmaxf(mx, accST[jt][r]);
        mx = fmaxf(mx, __shfl_xor(mx, 16));
        mx = fmaxf(mx, __shfl_xor(mx, 32));
        float mnew  = fmaxf(mrow, mx);
        float alpha = __expf(mrow - mnew);
        mrow = mnew;
        float p[4][4];
        float rs = 0.f;
#pragma unroll
        for (int jt = 0; jt < 4; ++jt)
#pragma unroll
            for (int r = 0; r < 4; ++r) {
                float e = __expf(accST[jt][r] - mnew);
                p[jt][r] = e;
                rs += e;
            }
        rs += __shfl_xor(rs, 16);
        rs += __shfl_xor(rs, 32);
        lrow = lrow * alpha + rs;

        if (g == 0) AL[cur][16*w + m] = alpha;

        // P(t64) -> PA[cur], direct b64 stores into A-frag layout
#pragma unroll
        for (int jt = 0; jt < 4; ++jt) {
            ushort4v u;
#pragma unroll
            for (int r = 0; r < 4; ++r) u[r] = f2bf(p[jt][r]);
            int frag = (w*2 + (jt >> 1))*64 + 16*(2*(jt & 1) + (g >> 1)) + m;
            *(ushort4v*)&PA[cur][frag*8 + 4*(g & 1)] = u;
        }
    }

    // final barrier: drains V(cend-1) DMA, syncs P(cend-1)/AL(cend-1)
    __syncthreads();

    // PV(cend-1) epilogue
    {
        const int cur = (cend - 1) & 1;
#pragma unroll
        for (int rt = 0; rt < 4; ++rt) {
            floatx4 a4 = *(const floatx4*)&AL[cur][64*wq + 16*rt + 4*g];
#pragma unroll
            for (int ct = 0; ct < 4; ++ct)
                accO[rt][ct] *= a4;
        }
#pragma unroll
        for (int ks = 0; ks < 2; ++ks) {
            bf16x8 pf[4];
#pragma unroll
            for (int rt = 0; rt < 4; ++rt)
                pf[rt] = *(const bf16x8*)
                    &PA[cur][((8*wq + rt*2 + ks)*64 + lane)*8];
#pragma unroll
            for (int ct = 0; ct < 4; ++ct) {
                int sidx = ks*16 + 4*cq + ct;
                bf16x8 vfrag = *(const bf16x8*)
                    &Vlds[cur][sidx*512 + lane*8];
#pragma unroll
                for (int rt = 0; rt < 4; ++rt)
                    accO[rt][ct] = __builtin_amdgcn_mfma_f32_16x16x32_bf16(
                                       pf[rt], vfrag, accO[rt][ct], 0, 0, 0);
            }
        }
    }

    // store unnormalized partial O (bf16) and per-query m,l
    const size_t tbase = ((size_t)(half*B_ + b)*32 + tile);
    unsigned short* Ob = Opart + tbase * (C_ * 128);
    float* ml = ML + tbase * 256;

    if (g == 0) {
        ml[16*w + m]       = mrow;
        ml[128 + 16*w + m] = lrow;
    }

#pragma unroll
    for (int rt = 0; rt < 4; ++rt)
#pragma unroll
        for (int ct = 0; ct < 4; ++ct) {
            int c  = 64*cq + 16*ct + m;
            int q0 = 64*wq + 16*rt + 4*g;
            ushort4v u4;
#pragma unroll
            for (int r = 0; r < 4; ++r) u4[r] = f2bf(accO[rt][ct][r]);
            *(ushort4v*)(Ob + (size_t)c*128 + q0) = u4;
        }
}

// ---------------------------------------------------------------------------
// Combine: S=2 static, c-split across 2 blocks, 128-query tiles (R2 verbatim).
// ---------------------------------------------------------------------------
__global__ __launch_bounds__(256) void combine_kernel(
    const unsigned short* __restrict__ Opart, const float* __restrict__ ML,
    const float* __restrict__ x, const float* __restrict__ gamma,
    float* __restrict__ out)
{
    __shared__ float sc0[128], sc1[128];
    const int tile  = blockIdx.x;       // 0..31
    const int chalf = blockIdx.y;
    const int b     = blockIdx.z;
    const int n0    = tile * 128;
    const int t     = threadIdx.x;

    if (t < 128) {
        const float* ml0 = ML + ((size_t)(0*B_ + b)*32 + tile)*256;
        const float* ml1 = ML + ((size_t)(1*B_ + b)*32 + tile)*256;
        float m0 = ml0[t], l0 = ml0[128 + t];
        float m1 = ml1[t], l1 = ml1[128 + t];
        float M  = fmaxf(m0, m1);
        float f0 = __expf(m0 - M), f1 = __expf(m1 - M);
        float L  = f0*l0 + f1*l1;
        float gm = gamma[0];
        sc0[t] = gm * f0 / L;
        sc1[t] = gm * f1 / L;
    }
    __syncthreads();

    const int nq = t & 31;              // query-quad (float4 column)
    const int cl = t >> 5;              // 0..7
    const float* xb = x   + (size_t)b*C_*N_;
    float*       ob = out + (size_t)b*C_*N_;
    const unsigned short* O0 = Opart + ((size_t)(0*B_ + b)*32 + tile)*(C_*128);
    const unsigned short* O1 = Opart + ((size_t)(1*B_ + b)*32 + tile)*(C_*128);

    float s0[4], s1[4];
#pragma unroll
    for (int k = 0; k < 4; ++k) { s0[k] = sc0[4*nq + k]; s1[k] = sc1[4*nq + k]; }

#pragma unroll 4
    for (int i = 0; i < 16; ++i) {
        int c = 128*chalf + 8*i + cl;
        float4 x4 = *(const float4*)(xb + (size_t)c*N_ + n0 + 4*nq);
        ushort4v a4 = *(const ushort4v*)(O0 + (size_t)c*128 + 4*nq);
        ushort4v b4 = *(const ushort4v*)(O1 + (size_t)c*128 + 4*nq);
        float4 y;
        y.x = s0[0]*bf2f(a4[0]) + s1[0]*bf2f(b4[0]) + x4.x;
        y.y = s0[1]*bf2f(a4[1]) + s1[1]*bf2f(b4[1]) + x4.y;
        y.z = s0[2]*bf2f(a4[2]) + s1[2]*bf2f(b4[2]) + x4.z;
        y.w = s0[3]*bf2f(a4[3]) + s1[3]*bf2f(b4[3]) + x4.w;
        *(float4*)(ob + (size_t)c*N_ + n0 + 4*nq) = y;
    }
}

// ---------------------------------------------------------------------------
extern "C" void kernel_launch(void* const* d_in, const int* in_sizes, int n_in,
                              void* d_out, int out_size, void* d_ws, size_t ws_size,
                              hipStream_t stream) {
    const float* x     = (const float*)d_in[0];
    const float* Wq    = (const float*)d_in[1];
    const float* bq    = (const float*)d_in[2];
    const float* Wk    = (const float*)d_in[3];
    const float* bk    = (const float*)d_in[4];
    const float* Wv    = (const float*)d_in[5];
    const float* bv    = (const float*)d_in[6];
    const float* gamma = (const float*)d_in[7];
    float* out = (float*)d_out;

    // ws layout (~29.3 MB, identical to R2):
    unsigned short* Qg = (unsigned short*)d_ws;            // 2 MiB
    unsigned short* Kg = Qg + (size_t)B_*N_*D_;            // 2 MiB
    unsigned short* Vg = Kg + (size_t)B_*N_*D_;            // 8 MiB
    unsigned short* Op = Vg + (size_t)B_*C_*N_;            // 16.8 MiB
    float* ML = (float*)(Op + (size_t)2*B_*32*C_*128);     // 256 KiB
    unsigned short* WbfA = (unsigned short*)(ML + (size_t)2*B_*32*256); // 192 KiB

    convert_w<<<dim3(96), 256, 0, stream>>>(Wq, Wk, Wv, WbfA);
    proj_kernel<<<dim3(64, 3, 4), 256, 0, stream>>>(x, WbfA, bq, bk, bv,
                                                    Qg, Kg, Vg);
    flash_kernel<<<dim3(8, 32), 512, 0, stream>>>(Qg, Kg, Vg, Op, ML);
    combine_kernel<<<dim3(32, 2, 4), 256, 0, stream>>>(Op, ML, x, gamma, out);
}

// Round 5
// 179.836 us; speedup vs baseline: 1.1060x; 1.0668x over previous
//
#include <hip/hip_runtime.h>

#define B_ 4
#define C_ 256
#define N_ 4096
#define D_ 64

typedef __bf16 bf16x8 __attribute__((ext_vector_type(8)));
typedef float floatx4 __attribute__((ext_vector_type(4)));
typedef unsigned short ushort8v __attribute__((ext_vector_type(8)));
typedef unsigned short ushort4v __attribute__((ext_vector_type(4)));
typedef unsigned short ushort2v __attribute__((ext_vector_type(2)));

static __device__ __forceinline__ unsigned short f2bf(float f) {
    unsigned int u = __builtin_bit_cast(unsigned int, f);
    u += 0x7fffu + ((u >> 16) & 1u);   // RNE
    return (unsigned short)(u >> 16);
}
static __device__ __forceinline__ float bf2f(unsigned short h) {
    unsigned int u = ((unsigned int)h) << 16;
    return __builtin_bit_cast(float, u);
}
// HW packed f32x2 -> bf16x2 (RNE), 1 VALU op instead of ~8 for manual pair
static __device__ __forceinline__ unsigned int cvt_pk_bf16(float lo, float hi) {
    unsigned int d;
    asm("v_cvt_pk_bf16_f32 %0, %1, %2" : "=v"(d) : "v"(lo), "v"(hi));
    return d;
}

// async global->LDS DMA, 16B/lane, dst = wave-uniform base + lane*16
#define GLOAD16(gp, lp)                                                      \
    __builtin_amdgcn_global_load_lds(                                        \
        (const __attribute__((address_space(1))) void*)(gp),                 \
        (__attribute__((address_space(3))) void*)(lp), 16, 0, 0)

// ---------------------------------------------------------------------------
// One-time W conversion into A-frag-native layout.
// ---------------------------------------------------------------------------
__global__ __launch_bounds__(256) void convert_w(
    const float* __restrict__ Wq, const float* __restrict__ Wk,
    const float* __restrict__ Wv, unsigned short* __restrict__ WbfA)
{
    int tid = blockIdx.x * 256 + threadIdx.x;   // 0..24575
    int p0  = tid * 4;                          // output short index
    int j0   = p0 & 7;
    int lane = (p0 >> 3) & 63;
    int sidx = p0 >> 9;
    int ft = sidx >> 3, ks = sidx & 7;
    int m  = lane & 15, g = lane >> 4;
    int f  = 16*ft + m;
    int c  = 32*ks + 8*g + j0;
    const float* src = (f < 64)  ? (Wq + (size_t)f * C_)
                     : (f < 128) ? (Wk + (size_t)(f - 64) * C_)
                                 : (Wv + (size_t)(f - 128) * C_);
    float4 v = *(const float4*)(src + c);
    uint2 u;
    u.x = cvt_pk_bf16(v.x, v.y);
    u.y = cvt_pk_bf16(v.z, v.w);
    *(uint2*)(WbfA + p0) = u;
}

// ---------------------------------------------------------------------------
// MFMA projection. Staging pack now uses v_cvt_pk_bf16_f32 (1 op per c-pair
// instead of ~8 VALU of manual RNE) — staging VALU was the suspected hog.
// ---------------------------------------------------------------------------
__global__ __launch_bounds__(256, 3) void proj_kernel(
    const float* __restrict__ x, const unsigned short* __restrict__ WbfA,
    const float* __restrict__ bq, const float* __restrict__ bk,
    const float* __restrict__ bv,
    unsigned short* __restrict__ Qg, unsigned short* __restrict__ Kg,
    unsigned short* __restrict__ Vg)
{
    __shared__ __align__(16) unsigned short smem[64 * 264];  // 33792 B
    unsigned short* xs = smem;          // x tile, swizzled [n][264]
    unsigned short* Lt = smem;          // epilogue tile [128][72] (union)

    const int n0 = blockIdx.x * 64;
    const int f0 = blockIdx.y * 128;
    const int b  = blockIdx.z;
    const int t  = threadIdx.x;
    const int w  = t >> 6;
    const int lane = t & 63;
    const int g  = lane >> 4;
    const int m  = lane & 15;

#pragma unroll
    for (int k = 0; k < 8; ++k) {
        int e  = t + 256 * k;           // 0..2047
        int cp = e >> 4;                // 0..127
        int c  = 2 * cp;
        int n4 = (e & 15) * 4;
        float4 v0 = *(const float4*)(x + ((size_t)b*C_ + c    )*N_ + n0 + n4);
        float4 v1 = *(const float4*)(x + ((size_t)b*C_ + c + 1)*N_ + n0 + n4);
        float a0[4] = {v0.x, v0.y, v0.z, v0.w};
        float a1[4] = {v1.x, v1.y, v1.z, v1.w};
#pragma unroll
        for (int j = 0; j < 4; ++j) {
            int n = n4 + j;
            unsigned int u = cvt_pk_bf16(a0[j], a1[j]);
            *(unsigned int*)&xs[n*264 + (((c >> 3) ^ (n & 7)) << 3) + (c & 7)] = u;
        }
    }

    float bias_[2][4];
#pragma unroll
    for (int mt = 0; mt < 2; ++mt)
#pragma unroll
        for (int r = 0; r < 4; ++r) {
            int fg = f0 + 32*w + 16*mt + 4*g + r;
            bias_[mt][r] = (fg < 64) ? bq[fg]
                         : (fg < 128) ? bk[fg - 64] : bv[fg - 128];
        }

    const unsigned short* Wa0 = WbfA + (size_t)(((f0 >> 4) + 2*w    )*8)*512
                              + lane*8;
    const unsigned short* Wa1 = WbfA + (size_t)(((f0 >> 4) + 2*w + 1)*8)*512
                              + lane*8;

    floatx4 acc[2][4];
#pragma unroll
    for (int mt = 0; mt < 2; ++mt)
#pragma unroll
        for (int nt = 0; nt < 4; ++nt) acc[mt][nt] = (floatx4){0.f,0.f,0.f,0.f};

    __syncthreads();   // x tile staged

#pragma unroll
    for (int ks = 0; ks < 8; ++ks) {
        bf16x8 af[2];
        af[0] = *(const bf16x8*)(Wa0 + ks*512);
        af[1] = *(const bf16x8*)(Wa1 + ks*512);
#pragma unroll
        for (int nt = 0; nt < 4; ++nt) {
            int n = 16*nt + m;
            bf16x8 bfr = *(const bf16x8*)
                &xs[n*264 + (((4*ks + g) ^ (n & 7)) << 3)];
#pragma unroll
            for (int mt = 0; mt < 2; ++mt)
                acc[mt][nt] = __builtin_amdgcn_mfma_f32_16x16x32_bf16(
                                  af[mt], bfr, acc[mt][nt], 0, 0, 0);
        }
    }

    __syncthreads();   // xs dead -> Lt overlay

#pragma unroll
    for (int mt = 0; mt < 2; ++mt)
#pragma unroll
        for (int nt = 0; nt < 4; ++nt)
#pragma unroll
            for (int r = 0; r < 4; ++r)
                Lt[(32*w + 16*mt + 4*g + r)*72 + 16*nt + m] =
                    f2bf(acc[mt][nt][r] + bias_[mt][r]);
    __syncthreads();

    if (f0 == 0) {
#pragma unroll
        for (int k = 0; k < 4; ++k) {
            int e   = t + 256 * k;
            int fq0 = (e >> 6) * 8;
            int nl  = e & 63;
            ushort8v u;
#pragma unroll
            for (int j = 0; j < 8; ++j) u[j] = Lt[(fq0 + j)*72 + nl];
            unsigned short* dst = (fq0 < 64)
                ? (Qg + ((size_t)b*N_ + n0 + nl)*D_ + fq0)
                : (Kg + ((size_t)b*N_ + n0 + nl)*D_ + (fq0 - 64));
            *(ushort8v*)dst = u;
        }
    } else {
        const int cb = f0 - 128;
#pragma unroll
        for (int k = 0; k < 4; ++k) {
            int e  = t + 256 * k;
            int fr = e >> 3;
            int n8 = (e & 7) * 8;
            ushort8v u = *(const ushort8v*)&Lt[fr*72 + n8];
            *(ushort8v*)(Vg + ((size_t)b*C_ + cb + fr)*N_ + n0 + n8) = u;
        }
    }
}

// ---------------------------------------------------------------------------
// MFMA flash attention: R2 structure VERBATIM (best measured: 86.4 us) with
// one micro-change: all f32->bf16 packing via v_cvt_pk_bf16_f32 (softmax
// P-pack 64 -> 8 VALU ops per wave-iter; epilogue likewise).
// 128-query tiles, 8 waves (512 thr), split-K 2, XCD-pinned grid,
// K dbuf + V via global_load_lds, __syncthreads drains.
// ---------------------------------------------------------------------------
__global__ __launch_bounds__(512, 2) void flash_kernel(
    const unsigned short* __restrict__ Qg, const unsigned short* __restrict__ Kg,
    const unsigned short* __restrict__ Vg,
    unsigned short* __restrict__ Opart, float* __restrict__ ML)
{
    __shared__ __align__(16) unsigned short Vlds[32 * 512];    // 32 KB
    __shared__ __align__(16) unsigned short Klds[2][8 * 512];  // 16 KB
    __shared__ __align__(16) unsigned short PA[16 * 64 * 8];   // 16 KB
    __shared__ float AL[128];

    const int g8   = blockIdx.x;        // half + 2*b  (XCD pin)
    const int tile = blockIdx.y;        // 0..31 (128-query tiles)
    const int half = g8 & 1;
    const int b    = g8 >> 1;
    const int n0   = tile * 128;
    const int t    = threadIdx.x;
    const int w    = t >> 6;            // 0..7
    const int lane = t & 63;
    const int g    = lane >> 4;
    const int m    = lane & 15;
    const int wq   = w >> 2;            // PV: query-half (0..1)
    const int cq   = w & 3;             // PV: channel-quarter (0..3)

    const unsigned short* Qb = Qg + ((size_t)b*N_ + n0)*D_;
    const unsigned short* Kb = Kg + (size_t)b*N_*D_;
    const unsigned short* Vb = Vg + (size_t)b*C_*N_;

    const int cstart = half * 32;
    const int cend   = cstart + 32;

    bf16x8 qf[2];
#pragma unroll
    for (int ks = 0; ks < 2; ++ks)
        qf[ks] = *(const bf16x8*)(Qb + (size_t)(16*w + m)*D_ + 32*ks + 8*g);

    floatx4 accO[4][4];
#pragma unroll
    for (int rt = 0; rt < 4; ++rt)
#pragma unroll
        for (int ct = 0; ct < 4; ++ct)
            accO[rt][ct] = (floatx4){0.f, 0.f, 0.f, 0.f};

    float mrow = -1e30f, lrow = 0.f;

    // prologue: DMA K(cstart) into Klds[0] (one 1KB wave-op per wave)
    {
        const unsigned short* gp =
            Kb + (size_t)(cstart*64 + 16*(w >> 1) + m)*D_ + 32*(w & 1) + 8*g;
        GLOAD16(gp, &Klds[0][w * 512]);
    }
    __syncthreads();

    for (int t64 = cstart; t64 < cend; ++t64) {
        const int j0 = t64 * 64;
        const int kb = (t64 - cstart) & 1;

        // DMA V(t64): 4 wave-ops per wave (32 total)
#pragma unroll
        for (int u = 0; u < 4; ++u) {
            int sidx = 4*w + u;
            int ks   = sidx >> 4;
            int cb   = sidx & 15;
            const unsigned short* gp =
                Vb + (size_t)(16*cb + m)*N_ + j0 + 32*ks + 8*g;
            GLOAD16(gp, &Vlds[sidx * 512]);
        }
        // DMA K(t64+1) into other buffer (1 wave-op per wave)
        if (t64 + 1 < cend) {
            const unsigned short* gp =
                Kb + (size_t)((t64+1)*64 + 16*(w >> 1) + m)*D_
                   + 32*(w & 1) + 8*g;
            GLOAD16(gp, &Klds[kb ^ 1][w * 512]);
        }

        // S^T = K*Q from Klds[kb]; each wave: its 16 queries x 64 keys
        floatx4 accST[4];
#pragma unroll
        for (int jt = 0; jt < 4; ++jt) accST[jt] = (floatx4){0.f,0.f,0.f,0.f};
#pragma unroll
        for (int ks = 0; ks < 2; ++ks)
#pragma unroll
            for (int jt = 0; jt < 4; ++jt) {
                bf16x8 kfr = *(const bf16x8*)
                    &Klds[kb][(jt*2 + ks)*512 + lane*8];
                accST[jt] = __builtin_amdgcn_mfma_f32_16x16x32_bf16(
                                kfr, qf[ks], accST[jt], 0, 0, 0);
            }

        // online softmax: in-register over 16 keys/lane + 2 shfls
        float mx = -1e30f;
#pragma unroll
        for (int jt = 0; jt < 4; ++jt)
#pragma unroll
            for (int r = 0; r < 4; ++r) mx = fmaxf(mx, accST[jt][r]);
        mx = fmaxf(mx, __shfl_xor(mx, 16));
        mx = fmaxf(mx, __shfl_xor(mx, 32));
        float mnew  = fmaxf(mrow, mx);
        float alpha = __expf(mrow - mnew);
        mrow = mnew;
        float p[4][4];
        float rs = 0.f;
#pragma unroll
        for (int jt = 0; jt < 4; ++jt)
#pragma unroll
            for (int r = 0; r < 4; ++r) {
                float e = __expf(accST[jt][r] - mnew);
                p[jt][r] = e;
                rs += e;
            }
        rs += __shfl_xor(rs, 16);
        rs += __shfl_xor(rs, 32);
        lrow = lrow * alpha + rs;

        if (g == 0) AL[16*w + m] = alpha;

        // P -> LDS: HW-packed bf16 pairs, b64 stores into A-frag layout
#pragma unroll
        for (int jt = 0; jt < 4; ++jt) {
            uint2 pu;
            pu.x = cvt_pk_bf16(p[jt][0], p[jt][1]);
            pu.y = cvt_pk_bf16(p[jt][2], p[jt][3]);
            int frag = (w*2 + (jt >> 1))*64 + 16*(2*(jt & 1) + (g >> 1)) + m;
            *(uint2*)&PA[frag*8 + 4*(g & 1)] = pu;
        }

        __syncthreads();   // barrier A: drains V DMA (+K prefetch)

        // PV: O = alpha*O + P V; wave covers query-half wq x channel-qtr cq
#pragma unroll
        for (int rt = 0; rt < 4; ++rt) {
            floatx4 a4 = *(const floatx4*)&AL[64*wq + 16*rt + 4*g];
#pragma unroll
            for (int ct = 0; ct < 4; ++ct)
                accO[rt][ct] *= a4;
        }
#pragma unroll
        for (int ks = 0; ks < 2; ++ks) {
            bf16x8 pf[4];
#pragma unroll
            for (int rt = 0; rt < 4; ++rt)
                pf[rt] = *(const bf16x8*)
                    &PA[((8*wq + rt*2 + ks)*64 + lane)*8];
#pragma unroll
            for (int ct = 0; ct < 4; ++ct) {
                int sidx = ks*16 + 4*cq + ct;
                bf16x8 vfrag = *(const bf16x8*)&Vlds[sidx*512 + lane*8];
#pragma unroll
                for (int rt = 0; rt < 4; ++rt)
                    accO[rt][ct] = __builtin_amdgcn_mfma_f32_16x16x32_bf16(
                                       pf[rt], vfrag, accO[rt][ct], 0, 0, 0);
            }
        }

        __syncthreads();   // barrier B
    }

    // store unnormalized partial O (bf16) and per-query m,l
    const size_t tbase = ((size_t)(half*B_ + b)*32 + tile);
    unsigned short* Ob = Opart + tbase * (C_ * 128);
    float* ml = ML + tbase * 256;

    if (g == 0) {
        ml[16*w + m]       = mrow;
        ml[128 + 16*w + m] = lrow;
    }

#pragma unroll
    for (int rt = 0; rt < 4; ++rt)
#pragma unroll
        for (int ct = 0; ct < 4; ++ct) {
            int c  = 64*cq + 16*ct + m;
            int q0 = 64*wq + 16*rt + 4*g;
            uint2 pu;
            pu.x = cvt_pk_bf16(accO[rt][ct][0], accO[rt][ct][1]);
            pu.y = cvt_pk_bf16(accO[rt][ct][2], accO[rt][ct][3]);
            *(uint2*)(Ob + (size_t)c*128 + q0) = pu;
        }
}

// ---------------------------------------------------------------------------
// Combine: S=2 static, c-split across 8 blocks (4 blocks/CU for BW), 128-q
// tiles.
// ---------------------------------------------------------------------------
__global__ __launch_bounds__(256) void combine_kernel(
    const unsigned short* __restrict__ Opart, const float* __restrict__ ML,
    const float* __restrict__ x, const float* __restrict__ gamma,
    float* __restrict__ out)
{
    __shared__ float sc0[128], sc1[128];
    const int tile   = blockIdx.x;      // 0..31
    const int cslice = blockIdx.y;      // 0..7 (32 channels each)
    const int b      = blockIdx.z;
    const int n0     = tile * 128;
    const int t      = threadIdx.x;

    if (t < 128) {
        const float* ml0 = ML + ((size_t)(0*B_ + b)*32 + tile)*256;
        const float* ml1 = ML + ((size_t)(1*B_ + b)*32 + tile)*256;
        float m0 = ml0[t], l0 = ml0[128 + t];
        float m1 = ml1[t], l1 = ml1[128 + t];
        float M  = fmaxf(m0, m1);
        float f0 = __expf(m0 - M), f1 = __expf(m1 - M);
        float L  = f0*l0 + f1*l1;
        float gm = gamma[0];
        sc0[t] = gm * f0 / L;
        sc1[t] = gm * f1 / L;
    }
    __syncthreads();

    const int nq = t & 31;              // query-quad (float4 column)
    const int cl = t >> 5;              // 0..7
    const float* xb = x   + (size_t)b*C_*N_;
    float*       ob = out + (size_t)b*C_*N_;
    const unsigned short* O0 = Opart + ((size_t)(0*B_ + b)*32 + tile)*(C_*128);
    const unsigned short* O1 = Opart + ((size_t)(1*B_ + b)*32 + tile)*(C_*128);

    float s0[4], s1[4];
#pragma unroll
    for (int k = 0; k < 4; ++k) { s0[k] = sc0[4*nq + k]; s1[k] = sc1[4*nq + k]; }

#pragma unroll
    for (int i = 0; i < 4; ++i) {
        int c = 32*cslice + 8*i + cl;
        float4 x4 = *(const float4*)(xb + (size_t)c*N_ + n0 + 4*nq);
        ushort4v a4 = *(const ushort4v*)(O0 + (size_t)c*128 + 4*nq);
        ushort4v b4 = *(const ushort4v*)(O1 + (size_t)c*128 + 4*nq);
        float4 y;
        y.x = s0[0]*bf2f(a4[0]) + s1[0]*bf2f(b4[0]) + x4.x;
        y.y = s0[1]*bf2f(a4[1]) + s1[1]*bf2f(b4[1]) + x4.y;
        y.z = s0[2]*bf2f(a4[2]) + s1[2]*bf2f(b4[2]) + x4.z;
        y.w = s0[3]*bf2f(a4[3]) + s1[3]*bf2f(b4[3]) + x4.w;
        *(float4*)(ob + (size_t)c*N_ + n0 + 4*nq) = y;
    }
}

// ---------------------------------------------------------------------------
extern "C" void kernel_launch(void* const* d_in, const int* in_sizes, int n_in,
                              void* d_out, int out_size, void* d_ws, size_t ws_size,
                              hipStream_t stream) {
    const float* x     = (const float*)d_in[0];
    const float* Wq    = (const float*)d_in[1];
    const float* bq    = (const float*)d_in[2];
    const float* Wk    = (const float*)d_in[3];
    const float* bk    = (const float*)d_in[4];
    const float* Wv    = (const float*)d_in[5];
    const float* bv    = (const float*)d_in[6];
    const float* gamma = (const float*)d_in[7];
    float* out = (float*)d_out;

    // ws layout (~29.3 MB):
    unsigned short* Qg = (unsigned short*)d_ws;            // 2 MiB
    unsigned short* Kg = Qg + (size_t)B_*N_*D_;            // 2 MiB
    unsigned short* Vg = Kg + (size_t)B_*N_*D_;            // 8 MiB
    unsigned short* Op = Vg + (size_t)B_*C_*N_;            // 16.8 MiB
    float* ML = (float*)(Op + (size_t)2*B_*32*C_*128);     // 256 KiB
    unsigned short* WbfA = (unsigned short*)(ML + (size_t)2*B_*32*256); // 192 KiB

    convert_w<<<dim3(96), 256, 0, stream>>>(Wq, Wk, Wv, WbfA);
    proj_kernel<<<dim3(64, 3, 4), 256, 0, stream>>>(x, WbfA, bq, bk, bv,
                                                    Qg, Kg, Vg);
    flash_kernel<<<dim3(8, 32), 512, 0, stream>>>(Qg, Kg, Vg, Op, ML);
    combine_kernel<<<dim3(32, 8, 4), 256, 0, stream>>>(Op, ML, x, gamma, out);
}